// Round 1
// baseline (204.627 us; speedup 1.0000x reference)
//
#include <hip/hip_runtime.h>

// DecoupledSOLOHead: SOLO mask decode + Matrix NMS (gaussian), MI355X/gfx950.
//
// R1 design notes:
//  - hard masks bit-packed to 950 x u64 per det (HW=60800=950*64 exactly, no tail)
//  - inter via popcount(AND) instead of [500,60800] @ [60800,500] f32 GEMM
//  - label_eq gating BEFORE popcount: only ~1/80 of pairs do real work
//  - exp() pulled out of the min: decay_coef[j] = exp(sigma * min_i(c_i^2 - d_ij^2))

#define N_DET 500
#define GRID  128
#define HDIM  200
#define WDIM  304
#define HW    (HDIM * WDIM)     // 60800
#define NWORDS (HW / 64)        // 950
#define MASK_THR 0.005f
#define SIGMA 2.0f

// ---------------- Kernel A: gather, soft/hard mask, bit-pack, per-mask stats ----
__global__ __launch_bounds__(512) void maskgen_kernel(
    const float* __restrict__ seg_x, const float* __restrict__ seg_y,
    const int* __restrict__ x_inds, const int* __restrict__ y_inds,
    const float* __restrict__ cate_scores,
    unsigned long long* __restrict__ packed,   // [N][NWORDS]
    float* __restrict__ sum_masks,             // [N]
    float* __restrict__ scores)                // [N] cate * seg_score
{
    const int n = blockIdx.x;
    const float* __restrict__ rx = seg_x + (size_t)x_inds[n] * HW;
    const float* __restrict__ ry = seg_y + (size_t)y_inds[n] * HW;
    unsigned long long* __restrict__ pk = packed + (size_t)n * NWORDS;

    const int tid  = threadIdx.x;
    const int lane = tid & 63;
    const int wav  = tid >> 6;                  // 0..7

    // contiguous word chunk per wave (coalesced 256B per word)
    const int chunk = (NWORDS + 7) / 8;         // 119
    const int w0 = wav * chunk;
    const int w1 = (w0 + chunk < NWORDS) ? (w0 + chunk) : NWORDS;

    float ssum = 0.0f;
    int   cnt  = 0;
    for (int w = w0; w < w1; ++w) {
        const int idx = (w << 6) + lane;
        const float p = rx[idx] * ry[idx];
        const bool hard = p > MASK_THR;
        const unsigned long long m = __ballot(hard);
        if (lane == 0) pk[w] = m;
        if (hard) { ssum += p; ++cnt; }
    }
    // wave reduce
    #pragma unroll
    for (int off = 32; off; off >>= 1) {
        ssum += __shfl_down(ssum, off);
        cnt  += __shfl_down(cnt,  off);
    }
    __shared__ float s_s[8];
    __shared__ int   s_c[8];
    if (lane == 0) { s_s[wav] = ssum; s_c[wav] = cnt; }
    __syncthreads();
    if (tid == 0) {
        float S = 0.0f; int C = 0;
        #pragma unroll
        for (int q = 0; q < 8; ++q) { S += s_s[q]; C += s_c[q]; }
        const float sm = (float)C;
        sum_masks[n] = sm;
        scores[n] = cate_scores[n] * (S / fmaxf(sm, 1.0f));
    }
}

// ---------------- Kernel B: same-class pairwise IoU via popcount, column max ----
__global__ __launch_bounds__(256) void pair_iou_kernel(
    const unsigned long long* __restrict__ packed,
    const float* __restrict__ sum_masks,
    const int* __restrict__ labels,
    float* __restrict__ d2col,    // [N][N] column-major: d2col[j*N + i] = iou^2
    float* __restrict__ comp2)    // [N] comp_iou^2
{
    const int j   = blockIdx.x;
    const int tid = threadIdx.x;

    // zero-fill our column (ws is poisoned 0xAA every launch)
    for (int i = tid; i < N_DET; i += 256) d2col[(size_t)j * N_DET + i] = 0.0f;
    __syncthreads();

    const int   lj = labels[j];
    const float sj = sum_masks[j];
    const unsigned long long* __restrict__ pj = packed + (size_t)j * NWORDS;

    __shared__ int red[4];
    float cmax = 0.0f;

    for (int i = 0; i < j; ++i) {            // block-uniform loop
        if (labels[i] != lj) continue;       // ~79/80 skipped
        const unsigned long long* __restrict__ pi = packed + (size_t)i * NWORDS;
        int part = 0;
        for (int w = tid; w < NWORDS; w += 256)
            part += __popcll(pi[w] & pj[w]);
        #pragma unroll
        for (int off = 32; off; off >>= 1) part += __shfl_down(part, off);
        const int lane = tid & 63, wav = tid >> 6;
        if (lane == 0) red[wav] = part;
        __syncthreads();
        if (tid == 0) {
            const int inter = red[0] + red[1] + red[2] + red[3];
            const float uni = sum_masks[i] + sj - (float)inter;
            const float iou = (float)inter / fmaxf(uni, 1e-6f);
            d2col[(size_t)j * N_DET + i] = iou * iou;
            cmax = fmaxf(cmax, iou);
        }
        __syncthreads();                     // red[] reuse guard
    }
    if (tid == 0) comp2[j] = cmax * cmax;
}

// ---------------- Kernel C: decay coef + final scores ----
__global__ __launch_bounds__(64) void decay_kernel(
    const float* __restrict__ d2col,
    const float* __restrict__ comp2,
    const float* __restrict__ scores,
    float* __restrict__ out)
{
    const int j = blockIdx.x;
    const int lane = threadIdx.x;
    float m = 1e30f;
    for (int i = lane; i < N_DET; i += 64)
        m = fminf(m, comp2[i] - d2col[(size_t)j * N_DET + i]);
    #pragma unroll
    for (int off = 32; off; off >>= 1)
        m = fminf(m, __shfl_down(m, off));
    if (lane == 0) out[j] = scores[j] * expf(SIGMA * m);
}

extern "C" void kernel_launch(void* const* d_in, const int* in_sizes, int n_in,
                              void* d_out, int out_size, void* d_ws, size_t ws_size,
                              hipStream_t stream) {
    const float* cate_scores = (const float*)d_in[0];
    const float* seg_x       = (const float*)d_in[1];
    const float* seg_y       = (const float*)d_in[2];
    const int*   labels      = (const int*)d_in[3];
    const int*   x_inds      = (const int*)d_in[4];
    const int*   y_inds      = (const int*)d_in[5];
    float* out = (float*)d_out;

    // workspace layout (all 8B-aligned); total ~4.81 MB
    char* ws = (char*)d_ws;
    unsigned long long* packed = (unsigned long long*)(ws + 0);        // 3,800,000 B
    float* d2col     = (float*)(ws + 3800000);                         // 1,000,000 B
    float* scores    = (float*)(ws + 4800000);                         //     2,000 B
    float* comp2     = (float*)(ws + 4802048);                         //     2,000 B
    float* sum_masks = (float*)(ws + 4804096);                         //     2,000 B

    maskgen_kernel <<<N_DET, 512, 0, stream>>>(seg_x, seg_y, x_inds, y_inds,
                                               cate_scores, packed, sum_masks, scores);
    pair_iou_kernel<<<N_DET, 256, 0, stream>>>(packed, sum_masks, labels, d2col, comp2);
    decay_kernel   <<<N_DET,  64, 0, stream>>>(d2col, comp2, scores, out);
}

// Round 2
// 131.325 us; speedup vs baseline: 1.5582x; 1.5582x over previous
//
#include <hip/hip_runtime.h>

// DecoupledSOLOHead: SOLO mask decode + Matrix NMS (gaussian), MI355X/gfx950.
//
// R2 changes vs R1 (which passed, 204.6 us, maskgen 75 us @ 17% HBM, VALUBusy 14%):
//  - maskgen: float4 loads (16B/lane), 4 ballots per 256-px group; packing layout
//    is an arbitrary-but-consistent pixel permutation (AND+popcount invariant)
//  - maskgen: 2 blocks per det (grid 1000 -> ~31 waves/CU) + finalize kernel
//  - pair_iou: labels/sum_masks in LDS, parallel match-list build, wave-per-pair
//    (no per-pair block barriers), pj fragment register-resident

#define N_DET 500
#define HW    (200 * 304)        // 60800
#define NGROUP 238               // ceil(60800/256); group 237 is half (128 px)
#define NWORDS 952               // NGROUP*4 u64 words per det
#define NW2    476               // NWORDS/2 (ulonglong2 granules)
#define MASK_THR 0.005f
#define SIGMA 2.0f

// ---------------- Kernel A: gather + soft*hard + bit-pack + partial stats ------
__global__ __launch_bounds__(512) void maskgen_kernel(
    const float* __restrict__ seg_x, const float* __restrict__ seg_y,
    const int* __restrict__ x_inds, const int* __restrict__ y_inds,
    unsigned long long* __restrict__ packed,   // [N][NWORDS]
    float* __restrict__ part_sum,              // [N*2]
    int*   __restrict__ part_cnt)              // [N*2]
{
    const int b = blockIdx.x;
    const int n = b >> 1;
    const int s = b & 1;                       // split half: groups [s*119, s*119+119)
    const float* __restrict__ rx = seg_x + (size_t)x_inds[n] * HW;
    const float* __restrict__ ry = seg_y + (size_t)y_inds[n] * HW;
    unsigned long long* __restrict__ pk = packed + (size_t)n * NWORDS;

    const int tid  = threadIdx.x;
    const int lane = tid & 63;
    const int wav  = tid >> 6;                 // 0..7

    float ssum = 0.0f;
    int   cnt  = 0;
    const int gend = s * 119 + 119;
    for (int g = s * 119 + wav; g < gend; g += 8) {
        const int base = (g << 8) + (lane << 2);   // g*256 + lane*4
        float4 x, y;
        if (base + 3 < HW) {                        // false only for g==237, lane>=32
            x = *(const float4*)(rx + base);
            y = *(const float4*)(ry + base);
        } else {
            x = make_float4(0.f, 0.f, 0.f, 0.f);
            y = x;
        }
        const float p0 = x.x * y.x, p1 = x.y * y.y, p2 = x.z * y.z, p3 = x.w * y.w;
        const bool h0 = p0 > MASK_THR, h1 = p1 > MASK_THR,
                   h2 = p2 > MASK_THR, h3 = p3 > MASK_THR;
        const unsigned long long m0 = __ballot(h0), m1 = __ballot(h1),
                                 m2 = __ballot(h2), m3 = __ballot(h3);
        if (lane < 4) {
            const unsigned long long mv = (lane == 0) ? m0 : (lane == 1) ? m1
                                        : (lane == 2) ? m2 : m3;
            pk[(g << 2) + lane] = mv;
        }
        ssum += (h0 ? p0 : 0.f) + (h1 ? p1 : 0.f) + (h2 ? p2 : 0.f) + (h3 ? p3 : 0.f);
        cnt  += (int)h0 + (int)h1 + (int)h2 + (int)h3;
    }
    // wave reduce
    #pragma unroll
    for (int off = 32; off; off >>= 1) {
        ssum += __shfl_down(ssum, off);
        cnt  += __shfl_down(cnt,  off);
    }
    __shared__ float s_s[8];
    __shared__ int   s_c[8];
    if (lane == 0) { s_s[wav] = ssum; s_c[wav] = cnt; }
    __syncthreads();
    if (tid == 0) {
        float S = 0.f; int C = 0;
        #pragma unroll
        for (int q = 0; q < 8; ++q) { S += s_s[q]; C += s_c[q]; }
        part_sum[b] = S;
        part_cnt[b] = C;
    }
}

// ---------------- Kernel A2: combine split partials -> sum_masks, scores -------
__global__ __launch_bounds__(512) void finalize_kernel(
    const float* __restrict__ part_sum, const int* __restrict__ part_cnt,
    const float* __restrict__ cate_scores,
    float* __restrict__ sum_masks, float* __restrict__ scores)
{
    const int n = threadIdx.x;
    if (n < N_DET) {
        const float S = part_sum[2 * n] + part_sum[2 * n + 1];
        const int   C = part_cnt[2 * n] + part_cnt[2 * n + 1];
        const float sm = (float)C;
        sum_masks[n] = sm;
        scores[n] = cate_scores[n] * (S / fmaxf(sm, 1.0f));
    }
}

// ---------------- Kernel B: same-class pairwise IoU via popcount ---------------
__global__ __launch_bounds__(256) void pair_iou_kernel(
    const unsigned long long* __restrict__ packed,
    const float* __restrict__ sum_masks,
    const int* __restrict__ labels,
    float* __restrict__ d2col,    // [N][N] col-major: d2col[j*N+i] = decay_iou^2
    float* __restrict__ comp2)    // [N] comp_iou^2
{
    const int j   = blockIdx.x;
    const int tid = threadIdx.x;
    const int lane = tid & 63, wav = tid >> 6;

    __shared__ int   s_lab[N_DET];
    __shared__ float s_sm[N_DET];
    __shared__ int   s_list[N_DET];
    __shared__ int   s_cnt;
    __shared__ float s_max[4];

    if (tid == 0) s_cnt = 0;
    for (int i = tid; i < N_DET; i += 256) {
        s_lab[i] = labels[i];
        s_sm[i]  = sum_masks[i];
        d2col[(size_t)j * N_DET + i] = 0.0f;   // ws is re-poisoned each launch
    }
    __syncthreads();

    const int   lj = s_lab[j];
    const float sj = s_sm[j];
    for (int i = tid; i < j; i += 256)
        if (s_lab[i] == lj) { const int p = atomicAdd(&s_cnt, 1); s_list[p] = i; }
    __syncthreads();
    const int cnt = s_cnt;

    // preload j's mask fragment into registers (476 ulonglong2 across 64 lanes)
    const ulonglong2* __restrict__ pj2 = (const ulonglong2*)(packed + (size_t)j * NWORDS);
    ulonglong2 bj[8];
    #pragma unroll
    for (int t = 0; t < 8; ++t) {
        const int w = lane + (t << 6);
        if (w < NW2) bj[t] = pj2[w];
        else { bj[t].x = 0ull; bj[t].y = 0ull; }
    }

    float wmax = 0.0f;
    for (int p = wav; p < cnt; p += 4) {       // one wave per pair
        const int i = s_list[p];
        const ulonglong2* __restrict__ pi2 = (const ulonglong2*)(packed + (size_t)i * NWORDS);
        int part = 0;
        #pragma unroll
        for (int t = 0; t < 8; ++t) {
            const int w = lane + (t << 6);
            if (w < NW2) {
                const ulonglong2 a = pi2[w];
                part += __popcll(a.x & bj[t].x) + __popcll(a.y & bj[t].y);
            }
        }
        #pragma unroll
        for (int off = 32; off; off >>= 1) part += __shfl_down(part, off);
        if (lane == 0) {
            const float uni = s_sm[i] + sj - (float)part;
            const float iou = (float)part / fmaxf(uni, 1e-6f);
            d2col[(size_t)j * N_DET + i] = iou * iou;
            wmax = fmaxf(wmax, iou);
        }
    }
    if (lane == 0) s_max[wav] = wmax;
    __syncthreads();
    if (tid == 0) {
        const float c = fmaxf(fmaxf(s_max[0], s_max[1]), fmaxf(s_max[2], s_max[3]));
        comp2[j] = c * c;
    }
}

// ---------------- Kernel C: decay coef + final scores --------------------------
__global__ __launch_bounds__(64) void decay_kernel(
    const float* __restrict__ d2col,
    const float* __restrict__ comp2,
    const float* __restrict__ scores,
    float* __restrict__ out)
{
    const int j = blockIdx.x;
    const int lane = threadIdx.x;
    float m = 1e30f;
    for (int i = lane; i < N_DET; i += 64)
        m = fminf(m, comp2[i] - d2col[(size_t)j * N_DET + i]);
    #pragma unroll
    for (int off = 32; off; off >>= 1)
        m = fminf(m, __shfl_down(m, off));
    if (lane == 0) out[j] = scores[j] * expf(SIGMA * m);
}

extern "C" void kernel_launch(void* const* d_in, const int* in_sizes, int n_in,
                              void* d_out, int out_size, void* d_ws, size_t ws_size,
                              hipStream_t stream) {
    const float* cate_scores = (const float*)d_in[0];
    const float* seg_x       = (const float*)d_in[1];
    const float* seg_y       = (const float*)d_in[2];
    const int*   labels      = (const int*)d_in[3];
    const int*   x_inds      = (const int*)d_in[4];
    const int*   y_inds      = (const int*)d_in[5];
    float* out = (float*)d_out;

    // workspace layout (16B-aligned blocks); total ~4.83 MB
    char* ws = (char*)d_ws;
    unsigned long long* packed = (unsigned long long*)(ws + 0);   // 500*952*8 = 3,808,000
    float* d2col     = (float*)(ws + 3808000);                    // 1,000,000
    float* part_sum  = (float*)(ws + 4808000);                    // 4,000
    int*   part_cnt  = (int*)  (ws + 4812000);                    // 4,000
    float* scores    = (float*)(ws + 4816000);                    // 2,000
    float* comp2     = (float*)(ws + 4818000);                    // 2,000
    float* sum_masks = (float*)(ws + 4820000);                    // 2,000

    maskgen_kernel <<<N_DET * 2, 512, 0, stream>>>(seg_x, seg_y, x_inds, y_inds,
                                                   packed, part_sum, part_cnt);
    finalize_kernel<<<1, 512, 0, stream>>>(part_sum, part_cnt, cate_scores,
                                           sum_masks, scores);
    pair_iou_kernel<<<N_DET, 256, 0, stream>>>(packed, sum_masks, labels, d2col, comp2);
    decay_kernel   <<<N_DET, 64, 0, stream>>>(d2col, comp2, scores, out);
}